// Round 1
// baseline (111.507 us; speedup 1.0000x reference)
//
#include <hip/hip_runtime.h>
#include <hip/hip_bf16.h>

typedef __attribute__((ext_vector_type(8))) short short8;
typedef __attribute__((ext_vector_type(4))) float f32x4;

#define T_DIM   336
#define N_NODES 325
#define O_DIM   96
#define BD      384      // B*D rows per node-group
#define ND      975      // N*D
#define XB      327600   // T_DIM * ND  (x stride per b)
#define KT      48       // t-values per K-step
#define NSTEP   7        // 336 / 48
#define MT      128      // rows per workgroup
#define HALO    12
#define ZW      72       // KT + 2*HALO
#define AST     104      // A tile LDS stride (bf16 elems), mult of 8, bank-friendly
#define BST     104

__device__ __forceinline__ unsigned short f2bf(float f) {
    union { __hip_bfloat16 h; unsigned short u; } cv;
    cv.h = __float2bfloat16(f);
    return cv.u;
}
__device__ __forceinline__ float bf2f(unsigned short u) {
    union { unsigned short u; __hip_bfloat16 h; } cv;
    cv.u = u;
    return __bfloat162float(cv.h);
}

// One workgroup: node nn, 128-row M-tile. C[m][o] = sum_t z*Ws + mean*(Wt-Ws), + biases.
// A = [z | mean] built in LDS each K-step; moving average via per-thread sliding window.
__global__ __launch_bounds__(512, 4)
void dlinear_gemm(const float* __restrict__ x,
                  const float* __restrict__ Ws,
                  const float* __restrict__ bs,
                  const float* __restrict__ Wt,
                  const float* __restrict__ bt,
                  float* __restrict__ Cws)
{
    __shared__ unsigned short zext[ZW][MT];       // [j][row] bf16, j = t0-12+j global t (clamped)
    __shared__ unsigned short Atile[MT][AST];     // cols 0..47 = z, 48..95 = mean
    __shared__ unsigned short Btile[O_DIM][BST];  // [o][k]: k 0..47 = Ws, 48..95 = Wt-Ws
    __shared__ float biasLds[O_DIM];

    const int tid  = threadIdx.x;
    const int bid  = blockIdx.x;
    const int nn   = bid / 3;
    const int m0   = (bid % 3) * MT;
    const int r_base = nn * BD + m0;

    if (tid < O_DIM) biasLds[tid] = bs[nn*O_DIM + tid] + bt[nn*O_DIM + tid];

    // staging constants: rl fixed per thread (512 % 128 == 0)
    const int rl   = tid & (MT-1);
    const int jb   = tid >> 7;                 // 0..3
    const int r    = r_base + rl;
    const int bI   = r / ND;
    const int rem  = r - bI*ND;
    const float* xp = x + bI*XB + rem;         // + t*ND indexes x[b, t, n', d']

    const float* Wsn = Ws + nn*(T_DIM*O_DIM);
    const float* Wtn = Wt + nn*(T_DIM*O_DIM);

    const int wave = tid >> 6;
    const int lane = tid & 63;
    const int wm = wave & 3;                   // 4 waves over M (32 rows each)
    const int wn = wave >> 2;                  // 2 waves over O (48 cols each)
    const int a_row0 = wm*32 + (lane & 15);
    const int a_row1 = a_row0 + 16;
    const int b_col0 = wn*48 + (lane & 15);
    const int ksub = (lane >> 4) * 8;

    f32x4 acc[2][3];
    #pragma unroll
    for (int i = 0; i < 2; ++i)
        #pragma unroll
        for (int j = 0; j < 3; ++j)
            acc[i][j] = (f32x4){0.f, 0.f, 0.f, 0.f};

    const int tr0 = jb * 12;                   // 12-wide t-span per thread for mean build

    for (int s = 0; s < NSTEP; ++s) {
        const int t0 = s * KT;
        __syncthreads();  // LDS safe to overwrite (also covers biasLds on s==0)

        // ---- stage z tile with halo: 72 x 128, coalesced along rows for fixed t
        #pragma unroll
        for (int i = 0; i < 18; ++i) {
            int j = jb + 4*i;                  // 0..71
            int tg = t0 - HALO + j;
            tg = tg < 0 ? 0 : (tg > T_DIM-1 ? T_DIM-1 : tg);  // replicate pad
            zext[j][rl] = f2bf(xp[tg * ND]);
        }
        // ---- stage B^T (bf16): [o][k], Wd = Wt - Ws computed in f32
        #pragma unroll
        for (int i = 0; i < 9; ++i) {
            int idx = tid + i*512;             // 48*96 = 4608
            int tr = idx / O_DIM;
            int o  = idx - tr*O_DIM;
            int go = (t0 + tr)*O_DIM + o;
            float wsv = Wsn[go];
            float wtv = Wtn[go];
            Btile[o][tr]      = f2bf(wsv);
            Btile[o][KT + tr] = f2bf(wtv - wsv);
        }
        __syncthreads();

        // ---- build A: copy z, sliding-window mean (window = zext[t .. t+24])
        {
            const int row = rl;
            float S = 0.f;
            #pragma unroll
            for (int j = 0; j < 25; ++j) S += bf2f(zext[tr0 + j][row]);
            unsigned int* arow = reinterpret_cast<unsigned int*>(&Atile[row][0]);
            #pragma unroll
            for (int u = 0; u < 12; u += 2) {
                int t = tr0 + u;
                unsigned int z0 = zext[t + HALO][row];
                unsigned int z1 = zext[t + HALO + 1][row];
                arow[t >> 1] = (z1 << 16) | z0;
                unsigned short mA = f2bf(S * (1.f/25.f));
                S += bf2f(zext[t + 25][row]) - bf2f(zext[t][row]);
                unsigned short mB = f2bf(S * (1.f/25.f));
                if (u + 2 < 12)   // compile-time after unroll; avoids OOB slide
                    S += bf2f(zext[t + 26][row]) - bf2f(zext[t + 1][row]);
                arow[(KT + t) >> 1] = ((unsigned int)mB << 16) | mA;
            }
        }
        __syncthreads();

        // ---- MFMA: effective K = 96 (48 z + 48 mean) = 3 chunks of 32
        #pragma unroll
        for (int kc = 0; kc < 3; ++kc) {
            const int k = kc*32 + ksub;
            short8 a0 = *(const short8*)&Atile[a_row0][k];
            short8 a1 = *(const short8*)&Atile[a_row1][k];
            short8 b0 = *(const short8*)&Btile[b_col0     ][k];
            short8 b1 = *(const short8*)&Btile[b_col0 + 16][k];
            short8 b2 = *(const short8*)&Btile[b_col0 + 32][k];
            acc[0][0] = __builtin_amdgcn_mfma_f32_16x16x32_bf16(a0, b0, acc[0][0], 0, 0, 0);
            acc[1][0] = __builtin_amdgcn_mfma_f32_16x16x32_bf16(a1, b0, acc[1][0], 0, 0, 0);
            acc[0][1] = __builtin_amdgcn_mfma_f32_16x16x32_bf16(a0, b1, acc[0][1], 0, 0, 0);
            acc[1][1] = __builtin_amdgcn_mfma_f32_16x16x32_bf16(a1, b1, acc[1][1], 0, 0, 0);
            acc[0][2] = __builtin_amdgcn_mfma_f32_16x16x32_bf16(a0, b2, acc[0][2], 0, 0, 0);
            acc[1][2] = __builtin_amdgcn_mfma_f32_16x16x32_bf16(a1, b2, acc[1][2], 0, 0, 0);
        }
    }

    // ---- epilogue: C/D layout col = lane&15, row = (lane>>4)*4 + j
    float* Cbase = Cws + (long)r_base * O_DIM;
    const int rsub = (lane >> 4) * 4;
    #pragma unroll
    for (int fm = 0; fm < 2; ++fm) {
        #pragma unroll
        for (int fn = 0; fn < 3; ++fn) {
            const int col = b_col0 + fn*16;
            const float bv = biasLds[col];
            #pragma unroll
            for (int j = 0; j < 4; ++j) {
                const int rowm = wm*32 + fm*16 + rsub + j;
                Cbase[rowm*O_DIM + col] = acc[fm][fn][j] + bv;
            }
        }
    }
}

// Layout fixup: Cws[nn][m][o] -> out[b][o][n2][d], where for fixed m:
// b = m/3, q = (m%3)*325 + nn (never wraps since 975 = 3*325).
// LDS tile transpose so both global sides get >=256B segments.
__global__ __launch_bounds__(256)
void dlinear_out(const float* __restrict__ Cws, float* __restrict__ out)
{
    __shared__ float tile[65][97];
    const int m   = blockIdx.x;           // 0..383
    const int nn0 = blockIdx.y * 65;      // 5 chunks of 65 (325 = 5*65)
    const int tid = threadIdx.x;

    for (int idx = tid; idx < 65*O_DIM; idx += 256) {
        int nni = idx / O_DIM;
        int o   = idx - nni*O_DIM;
        tile[nni][o] = Cws[(long)((nn0 + nni)*BD + m)*O_DIM + o];
    }
    __syncthreads();
    const int b = m / 3;
    const int g = m - b*3;
    float* obase = out + b*93600 + g*N_NODES + nn0;
    for (int idx = tid; idx < 65*O_DIM; idx += 256) {
        int o   = idx / 65;
        int nni = idx - o*65;
        obase[o*ND + nni] = tile[nni][o];
    }
}

extern "C" void kernel_launch(void* const* d_in, const int* in_sizes, int n_in,
                              void* d_out, int out_size, void* d_ws, size_t ws_size,
                              hipStream_t stream)
{
    const float* x  = (const float*)d_in[0];
    const float* Ws = (const float*)d_in[1];
    const float* bs = (const float*)d_in[2];
    const float* Wt = (const float*)d_in[3];
    const float* bt = (const float*)d_in[4];
    float* out = (float*)d_out;
    float* Cws = (float*)d_ws;   // needs 124800*96*4 = 47.9 MB of scratch

    dlinear_gemm<<<dim3(975), dim3(512), 0, stream>>>(x, Ws, bs, Wt, bt, Cws);
    dlinear_out<<<dim3(384, 5), dim3(256), 0, stream>>>(Cws, out);
}